// Round 12
// baseline (222.581 us; speedup 1.0000x reference)
//
#include <hip/hip_runtime.h>
#include <math.h>

static constexpr int BB  = 4;
static constexpr int HH  = 1024;
static constexpr int WW  = 1024;
static constexpr int HWP = HH * WW;       // 1<<20
static constexpr int NPIX = BB * HWP;     // 4<<20
static constexpr int WPR = WW / 64;       // 16 words per image row
static constexpr int PW  = HWP / 64;      // 16384 words per image bitplane
static constexpr int NT   = BB * 16 * 16; // 1024 hysteresis tiles (64x64 px, one wave each)
static constexpr int MAXR = 32;           // round bound (observed convergence <= ~7)
static constexpr int FCN  = 2 * MAXR + NT;// flags[MAXR] | counts[MAXR] | dirt[NT]
static constexpr int GRID_H = 256;        // hysteresis blocks (4 waves each) — all co-resident

// fused-stencil tile: 64 wide x 16 tall output (TY=16 -> ~28 KB LDS -> 5 blocks/CU)
static constexpr int TX = 64, TY = 16;
static constexpr int GH = 24,  GW = 72;   // gray   (pre-reflected halo)
static constexpr int HBH = 24, HBW = 68;  // hblur
static constexpr int VBH = 20, VBW = 68;  // vblur
static constexpr int MGH = 18, MGW = 66;  // mag

__device__ __forceinline__ int reflect_idx(int i, int n) {
    i = (i < 0) ? -i : i;                 // jnp.pad mode='reflect': -1 -> 1
    return (i >= n) ? (2 * n - 2 - i) : i;
}

// ---------- fused: gray -> hblur -> vblur -> sobel/mag -> dir -> NMS -> ballot ----------
__global__ void __launch_bounds__(256) k_front(const float* __restrict__ x,
                                               float* __restrict__ out0,
                                               unsigned long long* __restrict__ weakP,
                                               unsigned long long* __restrict__ strongP,
                                               int* __restrict__ fc,
                                               double w0, double w1, double w2) {
    __shared__ double A[GH * GW];         // gray, then vblur
    __shared__ double B[HBH * HBW];       // hblur, then mag
    __shared__ unsigned char P[TY * TX];  // quantized direction, center pixels

    const int tid = threadIdx.x;
    const int x0  = blockIdx.x * TX;
    const int y0  = blockIdx.y * TY;
    const int b   = blockIdx.z;
    const float* base = x + (size_t)b * 3u * HWP;

    if (blockIdx.x == 0 && blockIdx.y == 0 && b == 0) {
        for (int i = tid; i < FCN; i += 256) fc[i] = 0;   // flags/counts/dirt all 0
    }

    // S1: grayscale into A (rows/cols pre-reflected so later reads are raw)
    for (int idx = tid; idx < GH * GW; idx += 256) {
        int r = idx / GW, c = idx - r * GW;
        int gyr = reflect_idx(y0 + r - 4, HH);
        int gxr = reflect_idx(x0 + c - 4, WW);
        const float* rp = base + (size_t)gyr * WW;
        double rr = (double)rp[gxr];
        double gg = (double)rp[HWP + gxr];
        double bb = (double)rp[2 * HWP + gxr];
        A[idx] = rr * 0.299 + gg * 0.587 + bb * 0.114;
    }
    __syncthreads();

    // S2: hblur into B
    for (int idx = tid; idx < HBH * HBW; idx += 256) {
        int r = idx / HBW, c = idx - r * HBW;
        const double* g = &A[r * GW + c];
        double s;
        s  = w0 * g[0];
        s += w1 * g[1];
        s += w2 * g[2];
        s += w1 * g[3];
        s += w0 * g[4];
        B[idx] = s;
    }
    __syncthreads();

    // S3: vblur into A
    for (int idx = tid; idx < VBH * VBW; idx += 256) {
        int r = idx / VBW, c = idx - r * VBW;
        const double* h = &B[r * HBW + c];
        double s;
        s  = w0 * h[0];
        s += w1 * h[1 * HBW];
        s += w2 * h[2 * HBW];
        s += w1 * h[3 * HBW];
        s += w0 * h[4 * HBW];
        A[idx] = s;
    }
    __syncthreads();

    // S4: sobel magnitude into B (0 outside image = NMS zero pad) + dir bytes for center
    for (int idx = tid; idx < MGH * MGW; idx += 256) {
        int r = idx / MGW, c = idx - r * MGW;
        int gy = y0 + r - 1, gx = x0 + c - 1;
        double mg = 0.0;
        if (gy >= 0 && gy < HH && gx >= 0 && gx < WW) {
            int ym = gy > 0 ? gy - 1 : 0, yp = gy < HH - 1 ? gy + 1 : HH - 1;
            int xm = gx > 0 ? gx - 1 : 0, xp = gx < WW - 1 ? gx + 1 : WW - 1;
            auto BL = [&](int yy, int xx) -> double {
                return A[(yy - y0 + 2) * VBW + (xx - x0 + 2)];
            };
            double b00 = BL(ym, xm), b01 = BL(ym, gx), b02 = BL(ym, xp);
            double b10 = BL(gy, xm),                   b12 = BL(gy, xp);
            double b20 = BL(yp, xm), b21 = BL(yp, gx), b22 = BL(yp, xp);
            double gxv = -b00 + b02 - 2.0 * b10 + 2.0 * b12 - b20 + b22;
            double gyv = -b00 - 2.0 * b01 - b02 + b20 + 2.0 * b21 + b22;
            mg = sqrt(gxv * gxv + gyv * gyv + 1e-6);
            if (r >= 1 && r < TY + 1 && c >= 1 && c < TX + 1) {
                // octant classification == round(atan2(gy,gx)*4/pi) mod 8, boundary-exact
                double ax = fabs(gxv), ay = fabs(gyv);
                int p;
                if (ay < 0.41421356237309503 * ax)       // tan(22.5deg)
                    p = (gxv >= 0.0) ? 0 : 4;
                else if (ay < 2.4142135623730951 * ax)   // tan(67.5deg)
                    p = (gyv >= 0.0) ? ((gxv >= 0.0) ? 1 : 3)
                                     : ((gxv >= 0.0) ? 7 : 5);
                else
                    p = (gyv >= 0.0) ? 2 : 6;
                P[(r - 1) * TX + (c - 1)] = (unsigned char)p;
            }
        }
        B[r * MGW + c] = mg;
    }
    __syncthreads();

    // S5: NMS + thresholds + ballot (one wave = one 64px row-word)
    for (int k = 0; k < (TX * TY) / 256; ++k) {
        int idx = k * 256 + tid;
        int r = idx >> 6, c = idx & 63;
        double ctr = B[(r + 1) * MGW + (c + 1)];
        int p = P[idx];
        int dr = ((425   >> (2 * p)) & 3) - 1;
        int dc = ((36890 >> (2 * p)) & 3) - 1;
        double mp = B[(r + 1 + dr) * MGW + (c + 1 + dc)];
        double mn = B[(r + 1 - dr) * MGW + (c + 1 - dc)];
        bool ismax = ((ctr - mp) > 0.0) && ((ctr - mn) > 0.0);
        double sm = ismax ? ctr : 0.0;
        out0[(size_t)b * HWP + (size_t)(y0 + r) * WW + (x0 + c)] = (float)sm;
        bool strong = (sm > 0.2);
        bool weak   = (sm > 0.1) && !strong;
        unsigned long long wb = __ballot(weak);
        unsigned long long sb = __ballot(strong);
        if ((tid & 63) == 0) {
            int word = (y0 + r) * WPR + (x0 >> 6);
            weakP[(size_t)b * PW + word]   = wb;
            strongP[(size_t)b * PW + word] = sb;
        }
    }
}

// ---------------- hysteresis: single launch, 1024 wave-tiles, spin grid barrier ----------------
__device__ __forceinline__ unsigned long long ks_fill(unsigned long long g, unsigned long long p) {
    unsigned long long q;
    q = p;        g |= q & (g << 1);
    q &= q << 1;  g |= q & (g << 2);
    q &= q << 2;  g |= q & (g << 4);
    q &= q << 4;  g |= q & (g << 8);
    q &= q << 8;  g |= q & (g << 16);
    q &= q << 16; g |= q & (g << 32);
    q = p;        g |= q & (g >> 1);
    q &= q >> 1;  g |= q & (g >> 2);
    q &= q >> 2;  g |= q & (g >> 4);
    q &= q >> 4;  g |= q & (g >> 8);
    q &= q >> 8;  g |= q & (g >> 16);
    q &= q >> 16; g |= q & (g >> 32);
    return g;
}

__device__ __forceinline__ unsigned long long ald(const unsigned long long* p) {
    return __hip_atomic_load(p, __ATOMIC_RELAXED, __HIP_MEMORY_SCOPE_AGENT);
}

__global__ void __launch_bounds__(256) k_hyst(const unsigned long long* __restrict__ weakP,
                                              unsigned long long* __restrict__ strongP,
                                              float* __restrict__ out1,
                                              int* __restrict__ fc) {
    __shared__ int wch[4];
    __shared__ int s_live;
    int* flags  = fc;                         // [MAXR]
    int* counts = fc + MAXR;                  // [MAXR]
    int* dirt   = fc + 2 * MAXR;              // [NT]: last round tile changed (0 = initial)

    const int tid  = threadIdx.x;
    const int lane = tid & 63;
    const int wv   = tid >> 6;
    const int wid  = (blockIdx.x << 2) | wv;  // tile id: b(2b) | ty(4b) | tx(4b)
    const int b  = wid >> 8;
    const int ty = (wid >> 4) & 15;
    const int tx = wid & 15;
    const int tb = b << 8;

    const unsigned long long* wp = weakP + (size_t)b * PW;
    unsigned long long* spl      = strongP + (size_t)b * PW;
    const int row = (ty << 6) + lane;
    const int wi  = row * WPR + tx;
    unsigned long long w = wp[wi];
    unsigned long long s = spl[wi];           // fresh across kernel boundary

    for (int r = 1; r < MAXR; ++r) {
        // run local FP only if an 8-neighbor tile changed last round (round 1: all run)
        int go;
        if (r == 1) {
            go = 1;
        } else {
            const int rm = r - 1;
            auto D = [&](int t) -> int {
                return __hip_atomic_load(&dirt[t], __ATOMIC_RELAXED,
                                         __HIP_MEMORY_SCOPE_AGENT) == rm;
            };
            go = 0;
            if (ty > 0)  { go |= D(tb + ((ty - 1) << 4) + tx);
                           if (tx > 0)  go |= D(tb + ((ty - 1) << 4) + tx - 1);
                           if (tx < 15) go |= D(tb + ((ty - 1) << 4) + tx + 1); }
            if (ty < 15) { go |= D(tb + ((ty + 1) << 4) + tx);
                           if (tx > 0)  go |= D(tb + ((ty + 1) << 4) + tx - 1);
                           if (tx < 15) go |= D(tb + ((ty + 1) << 4) + tx + 1); }
            if (tx > 0)  go |= D(tb + (ty << 4) + tx - 1);
            if (tx < 15) go |= D(tb + (ty << 4) + tx + 1);
        }

        int changed = 0;
        if (go) {                             // wave-uniform
            unsigned long long ho = 0, top = 0, bot = 0;   // fresh halos (agent-coherent)
            if (tx > 0)  ho |= ald(&spl[wi - 1]) >> 63;
            if (tx < 15) ho |= ald(&spl[wi + 1]) << 63;
            if (lane == 0 && ty > 0) {
                int hw = (row - 1) * WPR + tx;
                unsigned long long hs = ald(&spl[hw]);
                top = (hs << 1) | hs | (hs >> 1);
                if (tx > 0)  top |= ald(&spl[hw - 1]) >> 63;
                if (tx < 15) top |= ald(&spl[hw + 1]) << 63;
            }
            if (lane == 63 && ty < 15) {
                int hw = (row + 1) * WPR + tx;
                unsigned long long hs = ald(&spl[hw]);
                bot = (hs << 1) | hs | (hs >> 1);
                if (tx > 0)  bot |= ald(&spl[hw - 1]) >> 63;
                if (tx < 15) bot |= ald(&spl[hw + 1]) << 63;
            }
            unsigned long long s0 = s;
            for (;;) {
                unsigned long long sp = (s << 1) | s | (s >> 1) | ho;
                unsigned long long up = __shfl_up(sp, 1);
                unsigned long long dn = __shfl_down(sp, 1);
                if (lane == 0)  up = top;
                if (lane == 63) dn = bot;
                unsigned long long g = s | (w & (up | sp | dn));
                g = ks_fill(g, w);
                int ch = (g != s);
                s = g;
                if (!__any(ch)) break;
            }
            changed = __any(s != s0) ? 1 : 0; // wave-uniform
            if (changed) {
                __hip_atomic_store(&spl[wi], s, __ATOMIC_RELAXED, __HIP_MEMORY_SCOPE_AGENT);
                if (lane == 0)
                    __hip_atomic_store(&dirt[tb + (ty << 4) + tx], r,
                                       __ATOMIC_RELAXED, __HIP_MEMORY_SCOPE_AGENT);
            }
        }

        if (lane == 0) wch[wv] = changed;
        __syncthreads();                      // drains this block's stores (vmcnt 0) + wch
        if (tid == 0) {
            if (wch[0] | wch[1] | wch[2] | wch[3])
                __hip_atomic_fetch_or(&flags[r], 1, __ATOMIC_RELEASE, __HIP_MEMORY_SCOPE_AGENT);
            __hip_atomic_fetch_add(&counts[r], 1, __ATOMIC_RELEASE, __HIP_MEMORY_SCOPE_AGENT);
            while (__hip_atomic_load(&counts[r], __ATOMIC_ACQUIRE,
                                     __HIP_MEMORY_SCOPE_AGENT) < GRID_H)
                __builtin_amdgcn_s_sleep(2);
            s_live = __hip_atomic_load(&flags[r], __ATOMIC_ACQUIRE, __HIP_MEMORY_SCOPE_AGENT);
        }
        __syncthreads();
        if (!s_live) break;                   // exact global fixed point
    }

    // epilogue: out1 from final strong plane; one bit-word -> 64 floats per thread
    const int gw = blockIdx.x * 256 + tid;    // word id 0..65535 == NPIX/64
    unsigned long long v = ald(&strongP[gw]);
    float4* o4 = (float4*)(out1 + (size_t)gw * 64);
    #pragma unroll
    for (int k = 0; k < 16; ++k) {
        float4 f;
        f.x = (float)((v >> (4 * k + 0)) & 1ull);
        f.y = (float)((v >> (4 * k + 1)) & 1ull);
        f.z = (float)((v >> (4 * k + 2)) & 1ull);
        f.w = (float)((v >> (4 * k + 3)) & 1ull);
        o4[k] = f;
    }
}

extern "C" void kernel_launch(void* const* d_in, const int* in_sizes, int n_in,
                              void* d_out, int out_size, void* d_ws, size_t ws_size,
                              hipStream_t stream) {
    const float* x = (const float*)d_in[0];
    float* out0 = (float*)d_out;          // suppressed magnitude [4,1,1024,1024]
    float* out1 = out0 + NPIX;            // edges [4,1,1024,1024]

    // workspace: weakP | strongP | fc (flags|counts|dirt)
    unsigned long long* weakP   = (unsigned long long*)d_ws;
    unsigned long long* strongP = weakP + (size_t)BB * PW;
    int* fc = (int*)(strongP + (size_t)BB * PW);

    // gaussian weights, f64 ops mirroring the reference
    double g0 = exp(-2.0), g1 = exp(-0.5), g2 = 1.0;
    double sum = (((g0 + g1) + g2) + g1) + g0;
    double w0 = g0 / sum, w1 = g1 / sum, w2 = g2 / sum;

    k_front<<<dim3(WW / TX, HH / TY, BB), dim3(256), 0, stream>>>(
        x, out0, weakP, strongP, fc, w0, w1, w2);

    k_hyst<<<dim3(GRID_H), dim3(256), 0, stream>>>(weakP, strongP, out1, fc);
}